// Round 16
// baseline (66.564 us; speedup 1.0000x reference)
//
#include <hip/hip_runtime.h>

#define BB 8
#define CC 128
#define HH 64
#define WW 64
#define OO 128
#define KT 9
#define HWs (HH * WW)

typedef __attribute__((ext_vector_type(8))) _Float16 half8;
typedef __attribute__((ext_vector_type(8))) short short8;
typedef __attribute__((ext_vector_type(8))) unsigned short ushort8;
typedef __attribute__((ext_vector_type(4))) float f32x4;

__device__ inline unsigned short f2bf(float f) {
    union { float f; unsigned int u; } x; x.f = f;
    unsigned int u = x.u;
    unsigned int r = u + 0x7fff + ((u >> 16) & 1);
    return (unsigned short)(r >> 16);
}

__device__ __forceinline__ void gload_lds16(const void* g, void* l) {
    __builtin_amdgcn_global_load_lds(
        (__attribute__((address_space(1))) void*)g,
        (__attribute__((address_space(3))) void*)l, 16, 0, 0);
}

// ---- prep 1: NCHW f32 -> NHWC f16 (proven) ----
__global__ __launch_bounds__(256) void prep_input(
    const float* __restrict__ in, _Float16* __restrict__ out) {
    __shared__ float t[CC][33];
    int b = blockIdx.y;
    int s0 = blockIdx.x * 32;
    int s = threadIdx.x & 31;
    int c0 = threadIdx.x >> 5;
    const float* ip = in + (size_t)b * CC * HWs;
#pragma unroll
    for (int c = 0; c < CC; c += 8)
        t[c + c0][s] = ip[(size_t)(c + c0) * HWs + s0 + s];
    __syncthreads();
    int ws = threadIdx.x >> 3;
    int cg = (threadIdx.x & 7) * 16;
    _Float16 v[16];
#pragma unroll
    for (int i = 0; i < 16; ++i) v[i] = (_Float16)t[cg + i][ws];
    _Float16* op = out + ((size_t)(b * HWs) + s0 + ws) * CC + cg;
    *(half8*)op = *(half8*)&v[0];
    *(half8*)(op + 8) = *(half8*)&v[8];
}

// ---- prep 2 (r12-proven): weight -> PRE-SWIZZLED wbf[k] (32 KB/tap) ----
__global__ __launch_bounds__(256) void prep_weight(
    const float* __restrict__ w, unsigned short* __restrict__ wbf) {
    int i = blockIdx.x * 256 + threadIdx.x;
    if (i >= KT * OO * CC) return;
    int k = i / (OO * CC);
    int r = i % (OO * CC);
    int o = r >> 7, c = r & 127;
    unsigned byte = (unsigned)(o * 256 + ((2 * c) ^ ((o & 15) << 4)));
    *(unsigned short*)((char*)wbf + (size_t)k * 32768 + byte) =
        f2bf(w[o * (CC * KT) + c * KT + k]);
}

// ---- kernel S: sampler. thread = (px, 16ch, tap). nt stores for As. ----
__global__ __launch_bounds__(256, 4) void deform_sample(
    const _Float16* __restrict__ inh, const float* __restrict__ offset,
    const float* __restrict__ mask, unsigned short* __restrict__ As,
    int b0, int lnb) {
    int nb = 1 << lnb;
    int hw = blockIdx.x;
    int xcd = hw & 7;
    int j = hw >> 3;
    int bl = xcd & (nb - 1);
    int task = (xcd >> lnb) * (144 << lnb) + j;
    int tap = task >> 7;
    int blk = task & 127;
    int tid = threadIdx.x;
    int px = blk * 32 + (tid >> 3);
    int cg = (tid & 7) * 16;
    int ho = px >> 6, wo = px & 63;
    int b = b0 + bl;

    const _Float16* base = inh + (size_t)b * HWs * CC;
    float oy = offset[(size_t)(b * 18 + 2 * tap) * HWs + ho * WW + wo];
    float ox = offset[(size_t)(b * 18 + 2 * tap + 1) * HWs + ho * WW + wo];
    float mm = mask[(size_t)(b * 9 + tap) * HWs + ho * WW + wo];

    int kh = tap / 3, kw = tap % 3;
    float py = (float)(ho - 1 + kh) + oy;
    float pxf = (float)(wo - 1 + kw) + ox;
    float fy = floorf(py), fx = floorf(pxf);
    float wy1 = py - fy, wx1 = pxf - fx;
    float wy0 = 1.f - wy1, wx0 = 1.f - wx1;
    int y0 = (int)fy, x0 = (int)fx;
    int y1 = y0 + 1, x1 = x0 + 1;
    bool vy0 = (y0 >= 0) & (y0 < HH);
    bool vy1 = (y1 >= 0) & (y1 < HH);
    bool vx0 = (x0 >= 0) & (x0 < WW);
    bool vx1 = (x1 >= 0) & (x1 < WW);
    float w00 = (vy0 & vx0) ? wy0 * wx0 * mm : 0.f;
    float w01 = (vy0 & vx1) ? wy0 * wx1 * mm : 0.f;
    float w10 = (vy1 & vx0) ? wy1 * wx0 * mm : 0.f;
    float w11 = (vy1 & vx1) ? wy1 * wx1 * mm : 0.f;
    int y0c = min(max(y0, 0), HH - 1), y1c = min(max(y1, 0), HH - 1);
    int x0c = min(max(x0, 0), WW - 1), x1c = min(max(x1, 0), WW - 1);
    const _Float16* p00 = base + (size_t)(y0c * WW + x0c) * CC + cg;
    const _Float16* p01 = base + (size_t)(y0c * WW + x1c) * CC + cg;
    const _Float16* p10 = base + (size_t)(y1c * WW + x0c) * CC + cg;
    const _Float16* p11 = base + (size_t)(y1c * WW + x1c) * CC + cg;
    half8 g00a = *(const half8*)p00, g00b = *(const half8*)(p00 + 8);
    half8 g01a = *(const half8*)p01, g01b = *(const half8*)(p01 + 8);
    half8 g10a = *(const half8*)p10, g10b = *(const half8*)(p10 + 8);
    half8 g11a = *(const half8*)p11, g11b = *(const half8*)(p11 + 8);

    ushort8 o0, o1;
#pragma unroll
    for (int q = 0; q < 8; ++q) {
        float s = w00 * (float)g00a[q] + w01 * (float)g01a[q] +
                  w10 * (float)g10a[q] + w11 * (float)g11a[q];
        o0[q] = f2bf(s);
    }
#pragma unroll
    for (int q = 0; q < 8; ++q) {
        float s = w00 * (float)g00b[q] + w01 * (float)g01b[q] +
                  w10 * (float)g10b[q] + w11 * (float)g11b[q];
        o1[q] = f2bf(s);
    }
    char* rowp = (char*)As + ((size_t)bl * 4096 + px) * 2304 + tap * 256;
    __builtin_nontemporal_store(o0, (ushort8*)(rowp + 2 * cg));
    __builtin_nontemporal_store(o1, (ushort8*)(rowp + 2 * cg + 16));
}

// ---- kernel G: pipelined GEMM, tile 128 px x 128 O, 8 waves ----
__global__ __launch_bounds__(512, 2) void deform_gemm(
    const unsigned short* __restrict__ As, const unsigned short* __restrict__ wbf,
    const float* __restrict__ bias, float* __restrict__ out, int b0) {
    __shared__ unsigned short Bl[2][OO * CC];   // 2 x 32 KB, rows pre-swizzled

    int bpx = blockIdx.x * 128;
    int tid = threadIdx.x;
    int wv = tid >> 6, l = tid & 63;
    int lr = l & 15, lg = l >> 4;

    // B staging: 8 waves x 4 KB per tap
    const char* bwsrc = (const char*)wbf + (size_t)wv * 4096 + (size_t)l * 16;
    const char* aptr = (const char*)As + (size_t)(bpx + wv * 16 + lr) * 2304 +
                       (size_t)lg * 16;

    f32x4 acc[8] = {};
    short8 areg[2][4];

    // ---- prologue: stage B(0); load A(0) ----
#pragma unroll
    for (int j2 = 0; j2 < 4; ++j2)
        gload_lds16(bwsrc + j2 * 1024, (char*)Bl[0] + wv * 4096 + j2 * 1024);
#pragma unroll
    for (int c32 = 0; c32 < 4; ++c32)
        areg[0][c32] =
            __builtin_nontemporal_load((const short8*)(aptr + c32 * 64));
    __syncthreads();

#pragma unroll
    for (int k = 0; k < KT; ++k) {
        // (1) issue B(k+1) DMA + A(k+1) nt loads BEFORE compute
        if (k < KT - 1) {
            const char* s = bwsrc + (size_t)(k + 1) * 32768;
            char* d = (char*)Bl[(k + 1) & 1] + wv * 4096;
#pragma unroll
            for (int j2 = 0; j2 < 4; ++j2)
                gload_lds16(s + j2 * 1024, d + j2 * 1024);
#pragma unroll
            for (int c32 = 0; c32 < 4; ++c32)
                areg[(k + 1) & 1][c32] = __builtin_nontemporal_load(
                    (const short8*)(aptr + (k + 1) * 256 + c32 * 64));
        }

        // (2) MFMA tap k: A regs, B from Bl[k&1] (pre-swizzled reads)
#pragma unroll
        for (int c32 = 0; c32 < 4; ++c32) {
            short8 af = areg[k & 1][c32];
#pragma unroll
            for (int n = 0; n < 8; ++n) {
                int o = n * 16 + lr;
                unsigned bb = (unsigned)(o * 256 + ((c32 * 64 + lg * 16) ^ (lr << 4)));
                short8 bf = *(const short8*)((const char*)Bl[k & 1] + bb);
                acc[n] = __builtin_amdgcn_mfma_f32_16x16x32_bf16(
                    af, bf, acc[n], 0, 0, 0);
            }
        }

        // (3) drain + barrier once per tap
        if (k < KT - 1) __syncthreads();
    }

    // epilogue
    int sp0 = bpx + wv * 16 + lg * 4;
    int b = b0 + (sp0 >> 12);
    int sp = sp0 & 4095;
    int ho = sp >> 6;
    int wo0 = sp & 63;
#pragma unroll
    for (int n = 0; n < 8; ++n) {
        int o = n * 16 + lr;
        float bs = bias[o];
        float4 v;
        v.x = acc[n][0] + bs;
        v.y = acc[n][1] + bs;
        v.z = acc[n][2] + bs;
        v.w = acc[n][3] + bs;
        *(float4*)(out + (size_t)(b * OO + o) * HWs + ho * WW + wo0) = v;
    }
}

extern "C" void kernel_launch(void* const* d_in, const int* in_sizes, int n_in,
                              void* d_out, int out_size, void* d_ws, size_t ws_size,
                              hipStream_t stream) {
    const float* inp    = (const float*)d_in[0];
    const float* offset = (const float*)d_in[1];
    const float* mask   = (const float*)d_in[2];
    const float* weight = (const float*)d_in[3];
    const float* bias   = (const float*)d_in[4];
    float* out = (float*)d_out;

    const size_t inh_b = (size_t)BB * HWs * CC * sizeof(_Float16);  // 8 MB
    const size_t wbf_b = (size_t)KT * OO * CC * sizeof(unsigned short);
    _Float16* inh = (_Float16*)d_ws;
    unsigned short* wbf = (unsigned short*)((char*)d_ws + inh_b);
    unsigned short* As = (unsigned short*)((char*)d_ws + inh_b + wbf_b);

    size_t avail = (ws_size > inh_b + wbf_b) ? ws_size - inh_b - wbf_b : 0;
    int lnb = 3;
    while (lnb > 0 && ((size_t)(1 << lnb)) * 4096u * 2304u > avail) --lnb;
    int nb = 1 << lnb;

    prep_input<<<dim3(128, 8), 256, 0, stream>>>(inp, inh);
    prep_weight<<<dim3((KT * OO * CC + 255) / 256), 256, 0, stream>>>(weight, wbf);
    for (int b0 = 0; b0 < BB; b0 += nb) {
        deform_sample<<<dim3(nb * 1152), 256, 0, stream>>>(
            inh, offset, mask, As, b0, lnb);
        deform_gemm<<<dim3(nb * 32), 512, 0, stream>>>(As, wbf, bias, out, b0);
    }
}

// Round 17
// 55.567 us; speedup vs baseline: 1.1979x; 1.1979x over previous
//
#include <hip/hip_runtime.h>

#define BB 8
#define CC 128
#define HH 64
#define WW 64
#define OO 128
#define KT 9
#define HWs (HH * WW)

typedef __attribute__((ext_vector_type(8))) _Float16 half8;
typedef __attribute__((ext_vector_type(8))) short short8;
typedef __attribute__((ext_vector_type(8))) unsigned short ushort8;
typedef __attribute__((ext_vector_type(4))) float f32x4;

__device__ inline unsigned short f2bf(float f) {
    union { float f; unsigned int u; } x; x.f = f;
    unsigned int u = x.u;
    unsigned int r = u + 0x7fff + ((u >> 16) & 1);
    return (unsigned short)(r >> 16);
}

__device__ __forceinline__ void gload_lds16(const void* g, void* l) {
    __builtin_amdgcn_global_load_lds(
        (__attribute__((address_space(1))) void*)g,
        (__attribute__((address_space(3))) void*)l, 16, 0, 0);
}

// ---- prep 1: NCHW f32 -> NHWC f16 (proven) ----
__global__ __launch_bounds__(256) void prep_input(
    const float* __restrict__ in, _Float16* __restrict__ out) {
    __shared__ float t[CC][33];
    int b = blockIdx.y;
    int s0 = blockIdx.x * 32;
    int s = threadIdx.x & 31;
    int c0 = threadIdx.x >> 5;
    const float* ip = in + (size_t)b * CC * HWs;
#pragma unroll
    for (int c = 0; c < CC; c += 8)
        t[c + c0][s] = ip[(size_t)(c + c0) * HWs + s0 + s];
    __syncthreads();
    int ws = threadIdx.x >> 3;
    int cg = (threadIdx.x & 7) * 16;
    _Float16 v[16];
#pragma unroll
    for (int i = 0; i < 16; ++i) v[i] = (_Float16)t[cg + i][ws];
    _Float16* op = out + ((size_t)(b * HWs) + s0 + ws) * CC + cg;
    *(half8*)op = *(half8*)&v[0];
    *(half8*)(op + 8) = *(half8*)&v[8];
}

// ---- prep 2 (r12-proven): weight -> PRE-SWIZZLED wbf[k] (32 KB/tap) ----
// element (k,o,c) at byte k*32768 + o*256 + ((2c) ^ ((o&15)<<4))
__global__ __launch_bounds__(256) void prep_weight(
    const float* __restrict__ w, unsigned short* __restrict__ wbf) {
    int i = blockIdx.x * 256 + threadIdx.x;
    if (i >= KT * OO * CC) return;
    int k = i / (OO * CC);
    int r = i % (OO * CC);
    int o = r >> 7, c = r & 127;
    unsigned byte = (unsigned)(o * 256 + ((2 * c) ^ ((o & 15) << 4)));
    *(unsigned short*)((char*)wbf + (size_t)k * 32768 + byte) =
        f2bf(w[o * (CC * KT) + c * KT + k]);
}

// ---- kernel S: sampler. thread = (px, 8ch, tap) -> ~50 VGPR, 8 waves/SIMD ----
// As layout identical to r13: byte px*2304 + tap*256 + ((2c)^((px&15)<<4))
__global__ __launch_bounds__(256, 4) void deform_sample(
    const _Float16* __restrict__ inh, const float* __restrict__ offset,
    const float* __restrict__ mask, unsigned short* __restrict__ As,
    int b0, int lnb) {
    int nb = 1 << lnb;
    int hw = blockIdx.x;
    int xcd = hw & 7;
    int j = hw >> 3;                          // [0, nb*288)
    int bl = xcd & (nb - 1);
    int task = (xcd >> lnb) * (288 << lnb) + j;   // [0, 2304)
    int tap = task >> 8;                      // 0..8
    int grp = task & 255;                     // 16-px group
    int tid = threadIdx.x;
    int px = grp * 16 + (tid >> 4);
    int cg = (tid & 15) * 8;                  // 8 channels per thread
    int ho = px >> 6, wo = px & 63;
    int b = b0 + bl;

    const _Float16* base = inh + (size_t)b * HWs * CC;
    float oy = offset[(size_t)(b * 18 + 2 * tap) * HWs + ho * WW + wo];
    float ox = offset[(size_t)(b * 18 + 2 * tap + 1) * HWs + ho * WW + wo];
    float mm = mask[(size_t)(b * 9 + tap) * HWs + ho * WW + wo];

    int kh = tap / 3, kw = tap % 3;
    float py = (float)(ho - 1 + kh) + oy;
    float pxf = (float)(wo - 1 + kw) + ox;
    float fy = floorf(py), fx = floorf(pxf);
    float wy1 = py - fy, wx1 = pxf - fx;
    float wy0 = 1.f - wy1, wx0 = 1.f - wx1;
    int y0 = (int)fy, x0 = (int)fx;
    int y1 = y0 + 1, x1 = x0 + 1;
    bool vy0 = (y0 >= 0) & (y0 < HH);
    bool vy1 = (y1 >= 0) & (y1 < HH);
    bool vx0 = (x0 >= 0) & (x0 < WW);
    bool vx1 = (x1 >= 0) & (x1 < WW);
    float w00 = (vy0 & vx0) ? wy0 * wx0 * mm : 0.f;
    float w01 = (vy0 & vx1) ? wy0 * wx1 * mm : 0.f;
    float w10 = (vy1 & vx0) ? wy1 * wx0 * mm : 0.f;
    float w11 = (vy1 & vx1) ? wy1 * wx1 * mm : 0.f;
    int y0c = min(max(y0, 0), HH - 1), y1c = min(max(y1, 0), HH - 1);
    int x0c = min(max(x0, 0), WW - 1), x1c = min(max(x1, 0), WW - 1);
    half8 g00 = *(const half8*)(base + (size_t)(y0c * WW + x0c) * CC + cg);
    half8 g01 = *(const half8*)(base + (size_t)(y0c * WW + x1c) * CC + cg);
    half8 g10 = *(const half8*)(base + (size_t)(y1c * WW + x0c) * CC + cg);
    half8 g11 = *(const half8*)(base + (size_t)(y1c * WW + x1c) * CC + cg);

    ushort8 o0;
#pragma unroll
    for (int q = 0; q < 8; ++q) {
        float s = w00 * (float)g00[q] + w01 * (float)g01[q] +
                  w10 * (float)g10[q] + w11 * (float)g11[q];
        o0[q] = f2bf(s);
    }
    char* rowp = (char*)As + ((size_t)bl * 4096 + px) * 2304 + tap * 256;
    unsigned sw = (unsigned)((px & 15) << 4);
    *(ushort8*)(rowp + ((2 * cg) ^ sw)) = o0;
}

// ---- kernel G (r13-proven): GEMM  M=nb*4096, N=128, K=1152 ----
// block = 256 thr / 4 waves; tile 64 px x 128 O; wave = 16 px x 128 O.
__global__ __launch_bounds__(256, 2) void deform_gemm(
    const unsigned short* __restrict__ As, const unsigned short* __restrict__ wbf,
    const float* __restrict__ bias, float* __restrict__ out, int b0) {
    __shared__ unsigned short Al[64 * 128];   // 16 KB, rows pre-swizzled
    __shared__ unsigned short Bl[OO * CC];    // 32 KB, rows pre-swizzled

    int bpx = blockIdx.x * 64;
    int tid = threadIdx.x;
    int wv = tid >> 6, l = tid & 63;
    int lr = l & 15, lg = l >> 4;

    const char* bwsrc = (const char*)wbf + (size_t)wv * 8192 + (size_t)l * 16;
    char* bldst = (char*)Bl + wv * 8192;

    f32x4 acc[8] = {};

    for (int k = 0; k < KT; ++k) {
        __syncthreads();   // bar A: previous tap's LDS reads complete
        // stage B(k): 8 KB per wave, zero-VGPR lds-direct
        {
            const char* s = bwsrc + (size_t)k * 32768;
#pragma unroll
            for (int j2 = 0; j2 < 8; ++j2)
                gload_lds16(s + j2 * 1024, bldst + j2 * 1024);
        }
        // stage A(k): 4 KB per wave (rows wv*16..wv*16+15), lane-linear dest
        {
#pragma unroll
            for (int j2 = 0; j2 < 4; ++j2) {
                int row = wv * 16 + j2 * 4 + lg;
                const char* s = (const char*)As +
                    (size_t)(bpx + row) * 2304 + (size_t)k * 256 + lr * 16;
                gload_lds16(s, (char*)Al + (wv * 16 + j2 * 4) * 256);
            }
        }
        __syncthreads();   // bar B: staging drained (compiler vmcnt(0))

        // MFMA: 4 K-steps x 8 N-frags
#pragma unroll
        for (int c32 = 0; c32 < 4; ++c32) {
            int arow = wv * 16 + lr;
            unsigned ab = (unsigned)(arow * 256 + ((c32 * 64 + lg * 16) ^ (lr << 4)));
            short8 af = *(const short8*)((const char*)Al + ab);
#pragma unroll
            for (int n = 0; n < 8; ++n) {
                int o = n * 16 + lr;
                unsigned bb = (unsigned)(o * 256 + ((c32 * 64 + lg * 16) ^ (lr << 4)));
                short8 bf = *(const short8*)((const char*)Bl + bb);
                acc[n] = __builtin_amdgcn_mfma_f32_16x16x32_bf16(
                    af, bf, acc[n], 0, 0, 0);
            }
        }
    }

    // epilogue: row px = bpx + wv*16 + lg*4 + j ; col o = n*16 + lr
    int sp0 = bpx + wv * 16 + lg * 4;
    int b = b0 + (sp0 >> 12);
    int sp = sp0 & 4095;
    int ho = sp >> 6;
    int wo0 = sp & 63;
#pragma unroll
    for (int n = 0; n < 8; ++n) {
        int o = n * 16 + lr;
        float bs = bias[o];
        float4 v;
        v.x = acc[n][0] + bs;
        v.y = acc[n][1] + bs;
        v.z = acc[n][2] + bs;
        v.w = acc[n][3] + bs;
        *(float4*)(out + (size_t)(b * OO + o) * HWs + ho * WW + wo0) = v;
    }
}

extern "C" void kernel_launch(void* const* d_in, const int* in_sizes, int n_in,
                              void* d_out, int out_size, void* d_ws, size_t ws_size,
                              hipStream_t stream) {
    const float* inp    = (const float*)d_in[0];
    const float* offset = (const float*)d_in[1];
    const float* mask   = (const float*)d_in[2];
    const float* weight = (const float*)d_in[3];
    const float* bias   = (const float*)d_in[4];
    float* out = (float*)d_out;

    const size_t inh_b = (size_t)BB * HWs * CC * sizeof(_Float16);  // 8 MB
    const size_t wbf_b = (size_t)KT * OO * CC * sizeof(unsigned short);
    _Float16* inh = (_Float16*)d_ws;
    unsigned short* wbf = (unsigned short*)((char*)d_ws + inh_b);
    unsigned short* As = (unsigned short*)((char*)d_ws + inh_b + wbf_b);

    size_t avail = (ws_size > inh_b + wbf_b) ? ws_size - inh_b - wbf_b : 0;
    int lnb = 3;
    while (lnb > 0 && ((size_t)(1 << lnb)) * 4096u * 2304u > avail) --lnb;
    int nb = 1 << lnb;

    prep_input<<<dim3(128, 8), 256, 0, stream>>>(inp, inh);
    prep_weight<<<dim3((KT * OO * CC + 255) / 256), 256, 0, stream>>>(weight, wbf);
    for (int b0 = 0; b0 < BB; b0 += nb) {
        deform_sample<<<dim3(nb * 2304), 256, 0, stream>>>(
            inh, offset, mask, As, b0, lnb);
        deform_gemm<<<dim3(nb * 64), 256, 0, stream>>>(As, wbf, bias, out, b0);
    }
}

// Round 19
// 51.899 us; speedup vs baseline: 1.2826x; 1.0707x over previous
//
#include <hip/hip_runtime.h>

#define BB 8
#define CC 128
#define HH 64
#define WW 64
#define OO 128
#define KT 9
#define HWs (HH * WW)

typedef __attribute__((ext_vector_type(8))) _Float16 half8;
typedef __attribute__((ext_vector_type(8))) short short8;
typedef __attribute__((ext_vector_type(8))) unsigned short ushort8;
typedef __attribute__((ext_vector_type(4))) float f32x4;

__device__ inline unsigned short f2bf(float f) {
    union { float f; unsigned int u; } x; x.f = f;
    unsigned int u = x.u;
    unsigned int r = u + 0x7fff + ((u >> 16) & 1);
    return (unsigned short)(r >> 16);
}

__device__ __forceinline__ void gload_lds16(const void* g, void* l) {
    __builtin_amdgcn_global_load_lds(
        (__attribute__((address_space(1))) void*)g,
        (__attribute__((address_space(3))) void*)l, 16, 0, 0);
}

// ---- fused prep, grid (576, 9):
//   y < 8 : NCHW f32 -> NHWC f16 for image y (only x < 128 active)
//   y == 8: weight -> PRE-SWIZZLED wbf[k] (needs all 576 x-blocks)
// weight element (k,o,c) at byte k*32768 + o*256 + ((2c) ^ ((o&15)<<4))
__global__ __launch_bounds__(256) void prep_fused(
    const float* __restrict__ in, _Float16* __restrict__ inh,
    const float* __restrict__ w, unsigned short* __restrict__ wbf) {
    if (blockIdx.y == 8) {
        int i = blockIdx.x * 256 + threadIdx.x;   // 576*256 = 147456 = KT*OO*CC
        if (i >= KT * OO * CC) return;
        int k = i / (OO * CC);
        int r = i % (OO * CC);
        int o = r >> 7, c = r & 127;
        unsigned byte = (unsigned)(o * 256 + ((2 * c) ^ ((o & 15) << 4)));
        *(unsigned short*)((char*)wbf + (size_t)k * 32768 + byte) =
            f2bf(w[o * (CC * KT) + c * KT + k]);
        return;
    }
    if (blockIdx.x >= 128) return;   // transpose needs only 128 x-blocks
    __shared__ float t[CC][33];
    int b = blockIdx.y;
    int s0 = blockIdx.x * 32;
    int s = threadIdx.x & 31;
    int c0 = threadIdx.x >> 5;
    const float* ip = in + (size_t)b * CC * HWs;
#pragma unroll
    for (int c = 0; c < CC; c += 8)
        t[c + c0][s] = ip[(size_t)(c + c0) * HWs + s0 + s];
    __syncthreads();
    int ws = threadIdx.x >> 3;
    int cg = (threadIdx.x & 7) * 16;
    _Float16 v[16];
#pragma unroll
    for (int i = 0; i < 16; ++i) v[i] = (_Float16)t[cg + i][ws];
    _Float16* op = inh + ((size_t)(b * HWs) + s0 + ws) * CC + cg;
    *(half8*)op = *(half8*)&v[0];
    *(half8*)(op + 8) = *(half8*)&v[8];
}

// ---- kernel S (r13-proven): sampler. thread = (px, 16ch, tap). ----
// As row = px within chunk, 2304 B/row; byte col ((2c) ^ ((px&15)<<4))
__global__ __launch_bounds__(256, 2) void deform_sample(
    const _Float16* __restrict__ inh, const float* __restrict__ offset,
    const float* __restrict__ mask, unsigned short* __restrict__ As,
    int b0, int lnb) {
    int nb = 1 << lnb;
    int hw = blockIdx.x;
    int xcd = hw & 7;
    int j = hw >> 3;
    int bl = xcd & (nb - 1);
    int task = (xcd >> lnb) * (144 << lnb) + j;
    int tap = task >> 7;
    int blk = task & 127;
    int tid = threadIdx.x;
    int px = blk * 32 + (tid >> 3);
    int cg = (tid & 7) * 16;
    int ho = px >> 6, wo = px & 63;
    int b = b0 + bl;

    const _Float16* base = inh + (size_t)b * HWs * CC;
    float oy = offset[(size_t)(b * 18 + 2 * tap) * HWs + ho * WW + wo];
    float ox = offset[(size_t)(b * 18 + 2 * tap + 1) * HWs + ho * WW + wo];
    float mm = mask[(size_t)(b * 9 + tap) * HWs + ho * WW + wo];

    int kh = tap / 3, kw = tap % 3;
    float py = (float)(ho - 1 + kh) + oy;
    float pxf = (float)(wo - 1 + kw) + ox;
    float fy = floorf(py), fx = floorf(pxf);
    float wy1 = py - fy, wx1 = pxf - fx;
    float wy0 = 1.f - wy1, wx0 = 1.f - wx1;
    int y0 = (int)fy, x0 = (int)fx;
    int y1 = y0 + 1, x1 = x0 + 1;
    bool vy0 = (y0 >= 0) & (y0 < HH);
    bool vy1 = (y1 >= 0) & (y1 < HH);
    bool vx0 = (x0 >= 0) & (x0 < WW);
    bool vx1 = (x1 >= 0) & (x1 < WW);
    float w00 = (vy0 & vx0) ? wy0 * wx0 * mm : 0.f;
    float w01 = (vy0 & vx1) ? wy0 * wx1 * mm : 0.f;
    float w10 = (vy1 & vx0) ? wy1 * wx0 * mm : 0.f;
    float w11 = (vy1 & vx1) ? wy1 * wx1 * mm : 0.f;
    int y0c = min(max(y0, 0), HH - 1), y1c = min(max(y1, 0), HH - 1);
    int x0c = min(max(x0, 0), WW - 1), x1c = min(max(x1, 0), WW - 1);
    const _Float16* p00 = base + (size_t)(y0c * WW + x0c) * CC + cg;
    const _Float16* p01 = base + (size_t)(y0c * WW + x1c) * CC + cg;
    const _Float16* p10 = base + (size_t)(y1c * WW + x0c) * CC + cg;
    const _Float16* p11 = base + (size_t)(y1c * WW + x1c) * CC + cg;
    half8 g00a = *(const half8*)p00, g00b = *(const half8*)(p00 + 8);
    half8 g01a = *(const half8*)p01, g01b = *(const half8*)(p01 + 8);
    half8 g10a = *(const half8*)p10, g10b = *(const half8*)(p10 + 8);
    half8 g11a = *(const half8*)p11, g11b = *(const half8*)(p11 + 8);

    ushort8 o0, o1;
#pragma unroll
    for (int q = 0; q < 8; ++q) {
        float s = w00 * (float)g00a[q] + w01 * (float)g01a[q] +
                  w10 * (float)g10a[q] + w11 * (float)g11a[q];
        o0[q] = f2bf(s);
    }
#pragma unroll
    for (int q = 0; q < 8; ++q) {
        float s = w00 * (float)g00b[q] + w01 * (float)g01b[q] +
                  w10 * (float)g10b[q] + w11 * (float)g11b[q];
        o1[q] = f2bf(s);
    }
    char* rowp = (char*)As + ((size_t)bl * 4096 + px) * 2304 + tap * 256;
    unsigned sw = (unsigned)((px & 15) << 4);
    *(ushort8*)(rowp + ((2 * cg) ^ sw)) = o0;
    *(ushort8*)(rowp + ((2 * cg + 16) ^ sw)) = o1;
}

// ---- kernel G (r13-proven): GEMM  M=nb*4096, N=128, K=1152 ----
// block = 256 thr / 4 waves; tile 64 px x 128 O; wave = 16 px x 128 O.
__global__ __launch_bounds__(256, 2) void deform_gemm(
    const unsigned short* __restrict__ As, const unsigned short* __restrict__ wbf,
    const float* __restrict__ bias, float* __restrict__ out, int b0) {
    __shared__ unsigned short Al[64 * 128];   // 16 KB, rows pre-swizzled
    __shared__ unsigned short Bl[OO * CC];    // 32 KB, rows pre-swizzled

    int bpx = blockIdx.x * 64;
    int tid = threadIdx.x;
    int wv = tid >> 6, l = tid & 63;
    int lr = l & 15, lg = l >> 4;

    const char* bwsrc = (const char*)wbf + (size_t)wv * 8192 + (size_t)l * 16;
    char* bldst = (char*)Bl + wv * 8192;

    f32x4 acc[8] = {};

    for (int k = 0; k < KT; ++k) {
        __syncthreads();   // bar A: previous tap's LDS reads complete
        // stage B(k): 8 KB per wave, zero-VGPR lds-direct
        {
            const char* s = bwsrc + (size_t)k * 32768;
#pragma unroll
            for (int j2 = 0; j2 < 8; ++j2)
                gload_lds16(s + j2 * 1024, bldst + j2 * 1024);
        }
        // stage A(k): 4 KB per wave (rows wv*16..wv*16+15), lane-linear dest
        {
#pragma unroll
            for (int j2 = 0; j2 < 4; ++j2) {
                int row = wv * 16 + j2 * 4 + lg;
                const char* s = (const char*)As +
                    (size_t)(bpx + row) * 2304 + (size_t)k * 256 + lr * 16;
                gload_lds16(s, (char*)Al + (wv * 16 + j2 * 4) * 256);
            }
        }
        __syncthreads();   // bar B: staging drained (compiler vmcnt(0))

        // MFMA: 4 K-steps x 8 N-frags
#pragma unroll
        for (int c32 = 0; c32 < 4; ++c32) {
            int arow = wv * 16 + lr;
            unsigned ab = (unsigned)(arow * 256 + ((c32 * 64 + lg * 16) ^ (lr << 4)));
            short8 af = *(const short8*)((const char*)Al + ab);
#pragma unroll
            for (int n = 0; n < 8; ++n) {
                int o = n * 16 + lr;
                unsigned bb = (unsigned)(o * 256 + ((c32 * 64 + lg * 16) ^ (lr << 4)));
                short8 bf = *(const short8*)((const char*)Bl + bb);
                acc[n] = __builtin_amdgcn_mfma_f32_16x16x32_bf16(
                    af, bf, acc[n], 0, 0, 0);
            }
        }
    }

    // epilogue: row px = bpx + wv*16 + lg*4 + j ; col o = n*16 + lr
    int sp0 = bpx + wv * 16 + lg * 4;
    int b = b0 + (sp0 >> 12);
    int sp = sp0 & 4095;
    int ho = sp >> 6;
    int wo0 = sp & 63;
#pragma unroll
    for (int n = 0; n < 8; ++n) {
        int o = n * 16 + lr;
        float bs = bias[o];
        float4 v;
        v.x = acc[n][0] + bs;
        v.y = acc[n][1] + bs;
        v.z = acc[n][2] + bs;
        v.w = acc[n][3] + bs;
        *(float4*)(out + (size_t)(b * OO + o) * HWs + ho * WW + wo0) = v;
    }
}

extern "C" void kernel_launch(void* const* d_in, const int* in_sizes, int n_in,
                              void* d_out, int out_size, void* d_ws, size_t ws_size,
                              hipStream_t stream) {
    const float* inp    = (const float*)d_in[0];
    const float* offset = (const float*)d_in[1];
    const float* mask   = (const float*)d_in[2];
    const float* weight = (const float*)d_in[3];
    const float* bias   = (const float*)d_in[4];
    float* out = (float*)d_out;

    const size_t inh_b = (size_t)BB * HWs * CC * sizeof(_Float16);  // 8 MB
    const size_t wbf_b = (size_t)KT * OO * CC * sizeof(unsigned short);
    _Float16* inh = (_Float16*)d_ws;
    unsigned short* wbf = (unsigned short*)((char*)d_ws + inh_b);
    unsigned short* As = (unsigned short*)((char*)d_ws + inh_b + wbf_b);

    size_t avail = (ws_size > inh_b + wbf_b) ? ws_size - inh_b - wbf_b : 0;
    int lnb = 3;
    while (lnb > 0 && ((size_t)(1 << lnb)) * 4096u * 2304u > avail) --lnb;
    int nb = 1 << lnb;

    prep_fused<<<dim3(576, 9), 256, 0, stream>>>(inp, inh, weight, wbf);
    for (int b0 = 0; b0 < BB; b0 += nb) {
        deform_sample<<<dim3(nb * 1152), 256, 0, stream>>>(
            inh, offset, mask, As, b0, lnb);
        deform_gemm<<<dim3(nb * 64), 256, 0, stream>>>(As, wbf, bias, out, b0);
    }
}